// Round 20
// baseline (832.617 us; speedup 1.0000x reference)
//
#include <hip/hip_runtime.h>
#include <math.h>

// ---------------------------------------------------------------------------
// ACARHead — R28: R27 (572us best) + k_prep_gn deleted via last-block-per-n
// GN fusion into k_attvirt. R20's fusion failed by replicating GN 8x; here
// GN runs EXACTLY ONCE per n: 64 device counters (cnt[n]); each attvirt
// block does __threadfence(); __syncthreads(); then 4 lane-leaders
// atomicAdd cnt[4bx+w]. The block seeing the 49th increment normalizes that
// n (49p x 512c, ~150KB) into gnT — finishers spread over blocks/time, no
// straggler. Stream order guarantees wo sees complete gnT. gnT borders
// zeroed each iteration by 512 extra k_mega blocks (re-poison safe); cnt
// zeroed by qkv pipe's zeroStats (extended to 192 words).
// Everything else identical to R27 (wo OCT=2 oc-split, 3-phase pipes).
// ---------------------------------------------------------------------------

typedef __bf16 bf16x8 __attribute__((ext_vector_type(8)));
typedef float  f32x4  __attribute__((ext_vector_type(4)));

#define NROI 64
#define CR   1024
#define HIDC 512
#define NCLS 60
#define PLANE (NROI * HIDC * 49)        // 1,605,632
#define ROWH 40
#define OCALL 4608
#define TAPSTR ((size_t)OCALL * 512)
#define WL (HIDC * HIDC * 9)
#define GNCNT 25088.0f                   // 512*49

#if defined(__has_builtin)
#  if __has_builtin(__builtin_amdgcn_global_load_lds)
#    define HAVE_GLL 1
#  endif
#endif

__device__ __forceinline__ void stage16(const void* g, void* lds_base, int lane) {
#ifdef HAVE_GLL
    __builtin_amdgcn_global_load_lds(
        (const __attribute__((address_space(1))) unsigned int*)g,
        (__attribute__((address_space(3))) unsigned int*)lds_base, 16, 0, 0);
#else
    *(uint4*)((char*)lds_base + lane * 16) = *(const uint4*)g;
#endif
}

__device__ __forceinline__ float bf2f(unsigned short h) {
    union { unsigned u; float f; } x; x.u = (unsigned)h << 16; return x.f;
}

__device__ __forceinline__ unsigned short f2bfu(float f) {
    return __builtin_bit_cast(unsigned short, (__bf16)f);
}

// bank-spread swizzle key for input rows (R23, kept)
__device__ __forceinline__ int swzkey(int r) {
    return (r & 3) ^ ((r >> 2) & 3);
}

// ---------- mega prologue: ab GEMM | weight transpose | borders ------------
// [0,48): ab; [48,4656): wAll row; [4656,5168): inT7 borders;
// [5168,5680): gnT borders (zeroed every iteration -> re-poison safe).
__global__ __launch_bounds__(256) void k_mega(
    const float* __restrict__ bg, const float* __restrict__ actor,
    const float* __restrict__ w1, const float* __restrict__ wfc1,
    const float* __restrict__ w2, const float* __restrict__ wq,
    const float* __restrict__ wk, const float* __restrict__ wv,
    const float* __restrict__ wo,
    float* __restrict__ A_T, float* __restrict__ Bp, float* __restrict__ roi,
    __bf16* __restrict__ wAll, __bf16* __restrict__ inT7,
    __bf16* __restrict__ gnT)
{
    const int b = blockIdx.x, tid = threadIdx.x;
    __shared__ __align__(16) char smem[18432];

    if (b < 48) {
        const int bx = b % 6, by = b / 6;
        const bool isA = bx < 4;
        const bool isRoi = (bx == 5);
        const int ocWg = by * 64;
        const int w = tid >> 6, lane = tid & 63;
        const int q = lane >> 4, l16 = lane & 15;
        __bf16* s_a = (__bf16*)smem;
        __bf16* s_b = s_a + 64 * ROWH;

        f32x4 acc[4];
#pragma unroll
        for (int nt = 0; nt < 4; ++nt) acc[nt] = (f32x4){0.f, 0.f, 0.f, 0.f};

        const int row = tid >> 2, part = tid & 3;
        for (int ch = 0; ch < 32; ++ch) {
            const int c0 = ch * 32;
            __syncthreads();
            if (isA) {
                const int gp = bx * 64 + row;
                bf16x8 val;
#pragma unroll
                for (int j = 0; j < 8; ++j)
                    val[j] = (__bf16)bg[(size_t)(c0 + part * 8 + j) * 256 + gp];
                *(bf16x8*)(&s_a[row * ROWH + part * 8]) = val;
            } else {
                const float* src = actor + (size_t)row * CR + c0 + part * 8;
                bf16x8 val;
#pragma unroll
                for (int j = 0; j < 8; ++j) val[j] = (__bf16)src[j];
                *(bf16x8*)(&s_a[row * ROWH + part * 8]) = val;
            }
            {
                const float* srcb = isRoi
                    ? (wfc1 + (size_t)(ocWg + row) * CR + c0 + part * 8)
                    : (w1 + (size_t)(ocWg + row) * (2 * CR)
                          + (isA ? 0 : CR) + c0 + part * 8);
                bf16x8 vb;
#pragma unroll
                for (int j = 0; j < 8; ++j) vb[j] = (__bf16)srcb[j];
                *(bf16x8*)(&s_b[row * ROWH + part * 8]) = vb;
            }
            __syncthreads();
            const bf16x8 af = *(const bf16x8*)(&s_a[(w * 16 + l16) * ROWH + q * 8]);
#pragma unroll
            for (int nt = 0; nt < 4; ++nt) {
                const bf16x8 bw = *(const bf16x8*)(&s_b[(nt * 16 + l16) * ROWH + q * 8]);
                acc[nt] = __builtin_amdgcn_mfma_f32_16x16x32_bf16(af, bw, acc[nt], 0, 0, 0);
            }
        }
#pragma unroll
        for (int r = 0; r < 4; ++r) {
#pragma unroll
            for (int nt = 0; nt < 4; ++nt) {
                const int mrow = w * 16 + q * 4 + r;
                const int oc = ocWg + nt * 16 + l16;
                if (isA)       A_T[(size_t)(bx * 64 + mrow) * 512 + oc] = acc[nt][r];
                else if (isRoi) roi[(size_t)mrow * 512 + oc] = fmaxf(acc[nt][r], 0.f);
                else           Bp[(size_t)mrow * 512 + oc] = acc[nt][r];
            }
        }
    } else if (b < 4656) {
        const int bid = b - 48;
        const float* src;
        if (bid < 512) src = w2 + (size_t)bid * 4608;
        else if (bid < 2048) {
            const int r = bid - 512;
            const float* bb = r < 512 ? wq : (r < 1024 ? wk : wv);
            src = bb + (size_t)(r & 511) * 4608;
        } else if (bid < 2560) src = wo + (size_t)(bid - 2048) * 4608;
        else if (bid < 4096) {
            const int r = bid - 2560;
            const float* bb = r < 512 ? wq : (r < 1024 ? wk : wv);
            src = bb + WL + (size_t)(r & 511) * 4608;
        } else src = wo + WL + (size_t)(bid - 4096) * 4608;
        float* s = (float*)smem;
        const float4* s4 = (const float4*)src;
        for (int i = tid; i < 1152; i += 256) ((float4*)s)[i] = s4[i];
        __syncthreads();
        for (int u = tid; u < 576; u += 256) {
            const int t = u / 64, o = u - (u / 64) * 64;
            const int swz = (o & 3) ^ ((bid >> 1) & 3);
            const int cbase = o * 8;
            unsigned pack[4];
#pragma unroll
            for (int h = 0; h < 4; ++h) {
                const unsigned short lo = f2bfu(s[(cbase + 2 * h) * 9 + t]);
                const unsigned short hi = f2bfu(s[(cbase + 2 * h + 1) * 9 + t]);
                pack[h] = ((unsigned)hi << 16) | lo;
            }
            const size_t cidx = (size_t)(o >> 2) * 32 + (size_t)swz * 8;
            *(uint4*)(wAll + (size_t)t * TAPSTR + (size_t)bid * 512 + cidx) =
                *(const uint4*)pack;
        }
    } else {
        // border zeros: [4656,5168) -> inT7, [5168,5680) -> gnT
        const int k = (b < 5168) ? (b - 4656) : (b - 5168);   // 0..511
        __bf16* base = (b < 5168) ? inT7 : gnT;
        const int n = k >> 3;
        const int j0 = (k & 7) * 4;
#pragma unroll
        for (int i = 0; i < 4; ++i) {
            const int jj = j0 + i;
            int sp;
            if (jj < 9) sp = jj;
            else if (jj < 18) sp = 63 + jj;
            else { const int t = jj - 18; sp = (1 + (t >> 1)) * 9 + (t & 1) * 8; }
            unsigned* d = (unsigned*)(base + ((size_t)n * 81 + sp) * 512);
            d[tid] = 0u;
        }
    }
}

// ---------- conv2 input: relu(A_T[p][c]+B[n][c]) -> inT2[vn][81][512] -----
__global__ __launch_bounds__(256) void k_prep_in2(
    const float* __restrict__ A_T, const float* __restrict__ B,
    __bf16* __restrict__ dst)
{
    const int vn = blockIdx.x;
    const int n = vn >> 2, quad = vn & 3;
    const int sp0 = blockIdx.y * 27;
    const float b0 = B[n * HIDC + threadIdx.x];
    const float b1 = B[n * HIDC + 256 + threadIdx.x];
    for (int sp = sp0; sp < sp0 + 27; ++sp) {
        const int r = sp / 9, w = sp % 9;
        const int p16 = ((quad >> 1) * 7 + r) * 16 + (quad & 1) * 7 + w;
        __bf16* d = dst + ((size_t)vn * 81 + sp) * 512;
        d[threadIdx.x]       = (__bf16)fmaxf(A_T[p16 * HIDC + threadIdx.x] + b0, 0.f);
        d[256 + threadIdx.x] = (__bf16)fmaxf(A_T[p16 * HIDC + 256 + threadIdx.x] + b1, 0.f);
    }
}

// ---------- 3-phase pipelined conv. MODE: 2=conv2, 0=qkv, 1=wo -----------
// OCT: oc tiles (4 -> 64 oc per block; 2 -> 32 oc per block, 2-gll weights)
template<int VN, int MODE, int OCT>
__global__ __launch_bounds__(256, (VN == 4) ? 2 : 3) void k_conv_pipe(
    const __bf16* __restrict__ inT,
    const __bf16* __restrict__ wAll, int ocBaseGl,
    __bf16* __restrict__ outb,
    float* __restrict__ zeroStats, float* __restrict__ gapZero,
    const float* __restrict__ resid, float* __restrict__ outf,
    __bf16* __restrict__ inT7out, float* __restrict__ gapOut)
{
    constexpr int MT = (VN == 4) ? 4 : 2;
    constexpr int SLOTS = VN * 324;                 // 1296 / 648
    constexpr int NSUB = (SLOTS + 255) / 256;       // 6 / 3
    constexpr int SBUF = NSUB * 256;
    constexpr int NI = NSUB / 3;                    // input glls/phase: 2 / 1
    constexpr int WTAP = OCT * 512;                 // halves per tap buffer
    constexpr int SWSZ = 2 * 3 * WTAP + ((OCT == 2) ? 1024 : 0);
    const int tid = threadIdx.x;
    const int w = tid >> 6, lane = tid & 63;
    const int q = lane >> 4, l16 = lane & 15;
    const int vn_l = (VN == 4) ? w : (w & 1);
    const int mh   = (VN == 4) ? 0 : (w >> 1);
    const int vnBase = blockIdx.x * VN;
    const int ocWg = blockIdx.y * (OCT * 16);

    if (zeroStats && blockIdx.x == 0 && blockIdx.y == 0 && tid < 192)
        zeroStats[tid] = 0.f;                       // stats[128] + cnt[64]
    if (gapZero && blockIdx.y == 0 && blockIdx.x < 16) {
        const float4 z = {0.f, 0.f, 0.f, 0.f};
        ((float4*)gapZero)[blockIdx.x * 512 + tid * 2]     = z;
        ((float4*)gapZero)[blockIdx.x * 512 + tid * 2 + 1] = z;
    }

    __shared__ __align__(16) __bf16 s_w[SWSZ];
    __shared__ __align__(16) __bf16 s_in[2 * SBUF * 8];

    unsigned iGo[NSUB];
#pragma unroll
    for (int s = 0; s < NSUB; ++s) {
        int idx = tid + s * 256;
        if (idx > SLOTS - 1) idx = SLOTS - 1;
        const int vnl = idx / 324, rem = idx - vnl * 324;
        const int r = rem >> 2, part = rem & 3;
        iGo[s] = (unsigned)(((vnBase + vnl) * 81 + r) * 512
                            + ((part ^ swzkey(r)) * 8));
    }
    unsigned wGo4 = 0;
    unsigned wGo2[2]; int wJ2[2];
    if constexpr (OCT == 4) {
        wGo4 = (unsigned)((ocBaseGl + ocWg + (tid >> 2)) * 512 + (tid & 3) * 8);
    } else {
#pragma unroll
        for (int k = 0; k < 2; ++k) {
            const int u = tid + k * 256;
            const int jj = (u >> 7) > 2 ? 2 : (u >> 7);
            const int row = (u >> 2) & 31, part = u & 3;
            wGo2[k] = (unsigned)((ocBaseGl + ocWg + row) * 512 + part * 8);
            wJ2[k] = jj;
        }
    }
    const int bOff = l16 * 32 + ((q ^ ((l16 >> 1) & 3)) << 3);

    int aLoc[MT];
#pragma unroll
    for (int mt = 0; mt < MT; ++mt) {
        int p = (mh * MT + mt) * 16 + l16;
        p = p > 48 ? 48 : p;
        aLoc[mt] = (p / 7) * 9 + (p % 7);
    }
    const int vb81 = vn_l * 81;

    f32x4 acc[MT][OCT];
#pragma unroll
    for (int a = 0; a < MT; ++a)
#pragma unroll
        for (int b = 0; b < OCT; ++b) acc[a][b] = (f32x4){0.f, 0.f, 0.f, 0.f};

    auto stageW = [&](int fn, int cc, int wparN) {
        if constexpr (OCT == 4) {
#pragma unroll
            for (int j = 0; j < 3; ++j)
                stage16(wAll + (size_t)(fn * 3 + j) * TAPSTR + wGo4 + cc,
                        (char*)s_w + (size_t)(wparN * 3 + j) * (WTAP * 2)
                                    + (size_t)w * 1024, lane);
        } else {
#pragma unroll
            for (int k = 0; k < 2; ++k) {
                const int ubase = (tid & ~63) + k * 256;
                char* dst;
                if (ubase < 384)
                    dst = (char*)s_w
                        + (size_t)(wparN * 3 + (ubase >> 7)) * (WTAP * 2)
                        + (size_t)(ubase & 127) * 16;
                else
                    dst = (char*)s_w + (size_t)(2 * 3 * WTAP) * 2
                        + (size_t)(ubase - 384) * 16;
                stage16(wAll + (size_t)(fn * 3 + wJ2[k]) * TAPSTR + wGo2[k] + cc,
                        dst, lane);
            }
        }
    };

#pragma unroll
    for (int s = 0; s < NSUB; ++s)
        stage16(inT + iGo[s],
                (char*)s_in + (size_t)(s * 256 + w * 64) * 16, lane);
    stageW(0, 0, 0);
    __syncthreads();

    for (int ch = 0; ch < 16; ++ch) {
        const int c0 = ch * 32;
        const int cur = ch & 1;
        const int nxt = cur ^ 1;
#pragma unroll
        for (int f = 0; f < 3; ++f) {
            const int P = ch * 3 + f;
            const int wpar = P & 1;
            {
                const int fn = (f == 2) ? 0 : (f + 1);
                const int cc = (f == 2) ? (c0 + 32) : c0;
                stageW(fn, cc, wpar ^ 1);
            }
#pragma unroll
            for (int u = 0; u < NI; ++u) {
                const int s = f * NI + u;
                stage16(inT + iGo[s] + c0 + 32,
                        (char*)s_in + (size_t)nxt * (SBUF * 16)
                                    + (size_t)(s * 256 + w * 64) * 16, lane);
            }
            if (f == 0) {
                if constexpr (OCT == 4) {
                    if constexpr (NI == 2) asm volatile("s_waitcnt vmcnt(5)" ::: "memory");
                    else                   asm volatile("s_waitcnt vmcnt(4)" ::: "memory");
                } else {
                    asm volatile("s_waitcnt vmcnt(3)" ::: "memory");
                }
            } else {
                if constexpr (OCT == 4) {
                    if constexpr (NI == 2) asm volatile("s_waitcnt vmcnt(7)" ::: "memory");
                    else                   asm volatile("s_waitcnt vmcnt(5)" ::: "memory");
                } else {
                    asm volatile("s_waitcnt vmcnt(4)" ::: "memory");
                }
            }
            __builtin_amdgcn_sched_barrier(0);
            __builtin_amdgcn_s_barrier();
            __builtin_amdgcn_sched_barrier(0);
#pragma unroll
            for (int j = 0; j < 3; ++j) {
                const int DT = f * 9 + j;
                bf16x8 bw[OCT];
#pragma unroll
                for (int nt = 0; nt < OCT; ++nt)
                    bw[nt] = *(const bf16x8*)(
                        &s_w[(wpar * 3 + j) * WTAP + nt * 512 + bOff]);
                bf16x8 af[MT];
#pragma unroll
                for (int mt = 0; mt < MT; ++mt) {
                    const int rl = aLoc[mt] + DT;
                    const int col = (q ^ swzkey(rl)) << 3;
                    af[mt] = *(const bf16x8*)(
                        &s_in[cur * (SBUF * 8) + (vb81 + rl) * 32 + col]);
                }
#pragma unroll
                for (int mt = 0; mt < MT; ++mt)
#pragma unroll
                    for (int nt = 0; nt < OCT; ++nt)
                        acc[mt][nt] = __builtin_amdgcn_mfma_f32_16x16x32_bf16(
                            af[mt], bw[nt], acc[mt][nt], 0, 0, 0);
            }
            __builtin_amdgcn_sched_barrier(0);
            __builtin_amdgcn_s_barrier();
        }
    }

    const int vn = vnBase + vn_l;
    float gsum[OCT];
#pragma unroll
    for (int nt = 0; nt < OCT; ++nt) gsum[nt] = 0.f;
#pragma unroll
    for (int mt = 0; mt < MT; ++mt) {
#pragma unroll
        for (int r = 0; r < 4; ++r) {
            const int p = (mh * MT + mt) * 16 + q * 4 + r;
            if (p >= 49) continue;
#pragma unroll
            for (int nt = 0; nt < OCT; ++nt) {
                const int oc = ocWg + nt * 16 + l16;
                const float v = acc[mt][nt][r];
                if constexpr (MODE == 2) {
                    const int n = vn >> 2, quad = vn & 3;
                    const int p14 = ((quad >> 1) * 7 + p / 7) * 14 + (quad & 1) * 7 + p % 7;
                    outb[((size_t)n * 196 + p14) * 512 + oc] = (__bf16)fmaxf(v, 0.f);
                } else if constexpr (MODE == 1) {
                    const size_t addr = ((size_t)vn * 49 + p) * 512 + oc;
                    const float res = v + resid[addr];
                    if (!gapOut) outf[addr] = res;
                    gsum[nt] += res;
                    if (inT7out) {
                        const int sp = (p / 7 + 1) * 9 + (p % 7 + 1);
                        inT7out[((size_t)vn * 81 + sp) * 512 + oc] = (__bf16)res;
                    }
                } else {
                    const int conv = oc >> 9;
                    outb[(size_t)conv * PLANE + ((size_t)p * 64 + vn) * 512 + (oc & 511)]
                        = (__bf16)v;
                }
            }
        }
    }
    if constexpr (MODE == 1) {
        if (gapOut) {
#pragma unroll
            for (int nt = 0; nt < OCT; ++nt)
                atomicAdd(gapOut + (size_t)vn * 512 + ocWg + nt * 16 + l16, gsum[nt]);
        }
    }
}

// ---------- fused maxpool + bf16 pack (interior) + fp32 residual ----------
__global__ __launch_bounds__(256) void k_pool_prep(
    const __bf16* __restrict__ x2, __bf16* __restrict__ inT7,
    float* __restrict__ xA)
{
    const int b = blockIdx.x;
    const int n = b / 49, p = b % 49;
    const int i = p / 7, j = p % 7;
    const int sp = (i + 1) * 9 + (j + 1);
#pragma unroll
    for (int k = 0; k < 2; ++k) {
        const int c = threadIdx.x + k * 256;
        float mx = -1e30f;
#pragma unroll
        for (int di = -1; di <= 1; ++di) {
            const int rr = 2 * i + di;
            if (rr < 0 || rr >= 14) continue;
#pragma unroll
            for (int dj = -1; dj <= 1; ++dj) {
                const int cc = 2 * j + dj;
                if (cc < 0 || cc >= 14) continue;
                mx = fmaxf(mx, (float)x2[((size_t)n * 196 + rr * 14 + cc) * 512 + c]);
            }
        }
        inT7[((size_t)n * 81 + sp) * 512 + c] = (__bf16)mx;
        xA[((size_t)n * 49 + p) * 512 + c] = mx;
    }
}

// ---------- fused attention + GN stats + last-block-per-n GN (R28) --------
__global__ __launch_bounds__(256) void k_attvirt(
    const __bf16* __restrict__ qT, const __bf16* __restrict__ kT,
    const __bf16* __restrict__ vT, float* __restrict__ virt,
    float* __restrict__ statsRaw, int* __restrict__ cnt,
    const float* __restrict__ gamma, const float* __restrict__ beta,
    __bf16* __restrict__ gnT)
{
    const int p = blockIdx.y;
    const int w = threadIdx.x >> 6, m = threadIdx.x & 63;
    const int n = blockIdx.x * 4 + w;
    __shared__ float s_q[4][HIDC];
    __shared__ float s_a[4][64];
    __shared__ int s_flag[4];
    {
        const uint4 v = ((const uint4*)(qT + ((size_t)p * 64 + n) * HIDC))[m];
        const unsigned* u = (const unsigned*)&v;
#pragma unroll
        for (int j = 0; j < 4; ++j) {
            s_q[w][m * 8 + 2 * j]     = bf2f((unsigned short)(u[j] & 0xffff));
            s_q[w][m * 8 + 2 * j + 1] = bf2f((unsigned short)(u[j] >> 16));
        }
    }
    __syncthreads();
    const uint4* krow = (const uint4*)(kT + ((size_t)p * 64 + m) * HIDC);
    float acc0 = 0.f, acc1 = 0.f;
    for (int i = 0; i < 64; ++i) {
        const uint4 v = krow[i];
        const unsigned* u = (const unsigned*)&v;
#pragma unroll
        for (int j = 0; j < 2; ++j) {
            acc0 = fmaf(s_q[w][i * 8 + 2 * j],     bf2f((unsigned short)(u[j] & 0xffff)), acc0);
            acc0 = fmaf(s_q[w][i * 8 + 2 * j + 1], bf2f((unsigned short)(u[j] >> 16)),    acc0);
        }
#pragma unroll
        for (int j = 2; j < 4; ++j) {
            acc1 = fmaf(s_q[w][i * 8 + 2 * j],     bf2f((unsigned short)(u[j] & 0xffff)), acc1);
            acc1 = fmaf(s_q[w][i * 8 + 2 * j + 1], bf2f((unsigned short)(u[j] >> 16)),    acc1);
        }
    }
    float acc = (acc0 + acc1) * 0.044194173824159216f;
    float mx = acc;
#pragma unroll
    for (int off = 32; off; off >>= 1) mx = fmaxf(mx, __shfl_xor(mx, off));
    const float e = expf(acc - mx);
    float s = e;
#pragma unroll
    for (int off = 32; off; off >>= 1) s += __shfl_xor(s, off);
    s_a[w][m] = e / s;
    __syncthreads();
    const int c0 = m * 8;
    float av[8];
#pragma unroll
    for (int j = 0; j < 8; ++j) av[j] = 0.f;
    for (int mm = 0; mm < 64; ++mm) {
        const float a = s_a[w][mm];
        const uint4 v = *(const uint4*)(vT + ((size_t)p * 64 + mm) * HIDC + c0);
        const unsigned* u = (const unsigned*)&v;
#pragma unroll
        for (int j = 0; j < 4; ++j) {
            av[2 * j]     = fmaf(a, bf2f((unsigned short)(u[j] & 0xffff)), av[2 * j]);
            av[2 * j + 1] = fmaf(a, bf2f((unsigned short)(u[j] >> 16)),    av[2 * j + 1]);
        }
    }
    float* o = virt + ((size_t)n * 49 + p) * 512 + c0;
    float ps = 0.f, pq = 0.f;
#pragma unroll
    for (int j = 0; j < 8; ++j) {
        o[j] = av[j];
        ps += av[j];
        pq = fmaf(av[j], av[j], pq);
    }
#pragma unroll
    for (int off = 32; off; off >>= 1) {
        ps += __shfl_xor(ps, off);
        pq += __shfl_xor(pq, off);
    }
    if (m == 0) {
        atomicAdd(statsRaw + n * 2, ps);
        atomicAdd(statsRaw + n * 2 + 1, pq);
    }

    // ---- last-block-per-n GN epilogue (replaces k_prep_gn) ----
    __threadfence();                 // all threads: order virt/stats writes
    __syncthreads();
    if (m == 0) {                    // lanes 0 of each wave -> n = 4bx+w
        const int prev = atomicAdd(cnt + n, 1);
        s_flag[w] = (prev == 48) ? 1 : 0;
    }
    __syncthreads();
#pragma unroll
    for (int nn = 0; nn < 4; ++nn) {
        if (s_flag[nn]) {
            __threadfence();         // acquire: see all 49 blocks' writes
            const int gn = blockIdx.x * 4 + nn;
            const float S = statsRaw[gn * 2], Q = statsRaw[gn * 2 + 1];
            const float mean = S / GNCNT;
            const float iv = rsqrtf(Q / GNCNT - mean * mean + 1e-5f);
            const int ca = threadIdx.x, cb = threadIdx.x + 256;
            const float g0 = gamma[ca], g1 = gamma[cb];
            const float b0 = beta[ca],  b1 = beta[cb];
            for (int pp = 0; pp < 49; ++pp) {
                const float* src = virt + ((size_t)gn * 49 + pp) * 512;
                __bf16* dpt = gnT + ((size_t)gn * 81
                                     + (pp / 7 + 1) * 9 + (pp % 7 + 1)) * 512;
                dpt[ca] = (__bf16)fmaxf((src[ca] - mean) * iv * g0 + b0, 0.f);
                dpt[cb] = (__bf16)fmaxf((src[cb] - mean) * iv * g1 + b1, 0.f);
            }
        }
    }
}

// ---------- final fc: out[n][k] = [roi | gap/49] . wfc2[k] ----------
__global__ __launch_bounds__(256) void k_final(
    const float* __restrict__ roi, const float* __restrict__ gap,
    const float* __restrict__ wfc2, float* __restrict__ out)
{
    const int n = blockIdx.x, tid = threadIdx.x;
    __shared__ float s[1024];
    s[tid]       = roi[(size_t)n * 512 + tid];
    s[tid + 256] = roi[(size_t)n * 512 + 256 + tid];
    s[tid + 512] = gap[(size_t)n * 512 + tid] * (1.f / 49.f);
    s[tid + 768] = gap[(size_t)n * 512 + 256 + tid] * (1.f / 49.f);
    __syncthreads();
    if (tid < 240) {
        const int k = tid >> 2, part = tid & 3;
        const float4* w4 = (const float4*)(wfc2 + (size_t)k * 1024 + part * 256);
        const float4* s4 = (const float4*)(s + part * 256);
        float a0 = 0.f, a1 = 0.f, a2 = 0.f, a3 = 0.f;
        for (int i = 0; i < 64; ++i) {
            const float4 wv = w4[i], sv = s4[i];
            a0 = fmaf(wv.x, sv.x, a0); a1 = fmaf(wv.y, sv.y, a1);
            a2 = fmaf(wv.z, sv.z, a2); a3 = fmaf(wv.w, sv.w, a3);
        }
        float acc = (a0 + a1) + (a2 + a3);
        acc += __shfl_xor(acc, 1);
        acc += __shfl_xor(acc, 2);
        if (part == 0) out[n * NCLS + k] = acc;
    }
}

// ---------------------------------------------------------------------------
extern "C" void kernel_launch(void* const* d_in, const int* in_sizes, int n_in,
                              void* d_out, int out_size, void* d_ws, size_t ws_size,
                              hipStream_t stream) {
    const float* bg    = (const float*)d_in[0];
    const float* actor = (const float*)d_in[1];
    const float* w1    = (const float*)d_in[2];
    const float* w2    = (const float*)d_in[3];
    const float* wq    = (const float*)d_in[4];
    const float* wk    = (const float*)d_in[5];
    const float* wv    = (const float*)d_in[6];
    const float* wo    = (const float*)d_in[7];
    const float* gamma = (const float*)d_in[8];
    const float* beta  = (const float*)d_in[9];
    const float* wfc1  = (const float*)d_in[10];
    const float* wfc2  = (const float*)d_in[11];
    float* out = (float*)d_out;
    float* ws  = (float*)d_ws;

    // ---- fp32 regions ----
    float* A_T   = ws;                        // 131,072
    float* Bp    = A_T + 131072;              // 32,768
    float* xA    = Bp + 32768;                // PLANE
    float* xB    = xA + PLANE;                // PLANE
    float* stats = xB + PLANE;                // 128 floats + 64 int counters
    int*   cnt   = (int*)(stats + 128);
    float* roi   = stats + 192;               // 32,768
    float* gap   = roi + 32768;               // 32,768
    float* fend  = gap + 32768;
    // ---- bf16 regions ----
    __bf16* x2h  = (__bf16*)fend;             // 64*196*512 = 6,422,528 halves
    float*  virt = (float*)x2h;               // aliases x2h (dead after pool)
    __bf16* inT2 = x2h + 6422528;             // 256*81*512 = 10,616,832
    __bf16* qkvT = inT2;                      // aliases inT2 (dead after conv2)
    __bf16* inT7 = inT2 + 10616832;           // 64*81*512  = 2,654,208
    __bf16* wAll = inT7 + 2654208;            // 9*4608*512 = 21,233,664
    __bf16* gnT  = wAll + (size_t)9 * OCALL * 512 + 262144;

    // 1: ab GEMM + weight transpose + inT7/gnT borders (merged)
    k_mega<<<5680, 256, 0, stream>>>(bg, actor, w1, wfc1, w2, wq, wk, wv, wo,
                                     A_T, Bp, roi, wAll, inT7, gnT);
    // 2: conv2 input planes
    k_prep_in2<<<dim3(256, 3), 256, 0, stream>>>(A_T, Bp, inT2);
    // 3: conv2 — 3-phase pipelined, VN4/OCT4 (64,8)=512 wgs = 2/CU
    k_conv_pipe<4, 2, 4><<<dim3(64, 8), 256, 0, stream>>>(
        inT2, wAll, 0, x2h, nullptr, nullptr,
        nullptr, nullptr, nullptr, nullptr);
    // 4: pool + pack + residual
    k_pool_prep<<<64 * 49, 256, 0, stream>>>(x2h, inT7, xA);

    float* xin = xA;
    float* xout = xB;
    for (int d = 0; d < 2; ++d) {
        // 5/8: fused qkv — VN2/OCT4 (32,24)=768 wgs = 3/CU; zeroes stats+cnt
        k_conv_pipe<2, 0, 4><<<dim3(32, 24), 256, 0, stream>>>(
            inT7, wAll, 512 + d * 2048, qkvT, stats,
            d == 1 ? gap : nullptr,
            nullptr, nullptr, nullptr, nullptr);
        // 6/9: attention + GN stats + last-block-per-n GN (k_prep_gn deleted)
        k_attvirt<<<dim3(16, 49), 256, 0, stream>>>(
            qkvT, qkvT + PLANE, qkvT + 2 * PLANE, virt, stats, cnt,
            gamma + d * HIDC, beta + d * HIDC, gnT);
        // 7/10: wo conv — VN2/OCT2 oc-split: (32,16)=512 wgs = 2/CU
        k_conv_pipe<2, 1, 2><<<dim3(32, 16), 256, 0, stream>>>(
            gnT, wAll, 2048 + d * 2048, nullptr, nullptr, nullptr,
            xin, xout, d == 0 ? inT7 : nullptr, d == 1 ? gap : nullptr);
        float* t = xin; xin = xout; xout = t;
    }
    // 11: final fc from roi + fused gap
    k_final<<<64, 256, 0, stream>>>(roi, gap, wfc2, out);
}

// Round 21
// 570.228 us; speedup vs baseline: 1.4601x; 1.4601x over previous
//
#include <hip/hip_runtime.h>
#include <math.h>

// ---------------------------------------------------------------------------
// ACARHead — R29: revert R28 (last-block GN fusion: per-block __threadfence
// = L2 writeback storm on non-coherent XCDs; attvirt 15->195us). This is
// R27 exactly — session best, 572.3us:
//   - k_mega: ab GEMM + vectorized weight transpose + inT7 borders (merged)
//   - conv2 VN4/OCT4 (64,8)=2/CU; qkv VN2/OCT4 (32,24)=3/CU;
//     wo VN2/OCT2 oc-split (32,16)=2/CU — all on the 3-phase gll pipeline
//     (counted vmcnt, dbuf s_w/s_in; T3+T4)
//   - standalone k_prep_gn feeding the wo pipe (cheaper than any in-kernel
//     cross-block coordination on this chip)
//   - scalar-broadcast k_attvirt
// Ledger: 726.7 -> 572.3 via gapfinal-kill, grid-fill, 3-phase pipe,
// wo-split, mega-prologue, wo oc-split.
// ---------------------------------------------------------------------------

typedef __bf16 bf16x8 __attribute__((ext_vector_type(8)));
typedef float  f32x4  __attribute__((ext_vector_type(4)));

#define NROI 64
#define CR   1024
#define HIDC 512
#define NCLS 60
#define PLANE (NROI * HIDC * 49)        // 1,605,632
#define ROWH 40
#define OCALL 4608
#define TAPSTR ((size_t)OCALL * 512)
#define WL (HIDC * HIDC * 9)
#define GNCNT 25088.0f                   // 512*49

#if defined(__has_builtin)
#  if __has_builtin(__builtin_amdgcn_global_load_lds)
#    define HAVE_GLL 1
#  endif
#endif

__device__ __forceinline__ void stage16(const void* g, void* lds_base, int lane) {
#ifdef HAVE_GLL
    __builtin_amdgcn_global_load_lds(
        (const __attribute__((address_space(1))) unsigned int*)g,
        (__attribute__((address_space(3))) unsigned int*)lds_base, 16, 0, 0);
#else
    *(uint4*)((char*)lds_base + lane * 16) = *(const uint4*)g;
#endif
}

__device__ __forceinline__ float bf2f(unsigned short h) {
    union { unsigned u; float f; } x; x.u = (unsigned)h << 16; return x.f;
}

__device__ __forceinline__ unsigned short f2bfu(float f) {
    return __builtin_bit_cast(unsigned short, (__bf16)f);
}

// bank-spread swizzle key for input rows (R23, kept)
__device__ __forceinline__ int swzkey(int r) {
    return (r & 3) ^ ((r >> 2) & 3);
}

// ---------- mega prologue: ab GEMM | weight transpose | inT7 borders -------
__global__ __launch_bounds__(256) void k_mega(
    const float* __restrict__ bg, const float* __restrict__ actor,
    const float* __restrict__ w1, const float* __restrict__ wfc1,
    const float* __restrict__ w2, const float* __restrict__ wq,
    const float* __restrict__ wk, const float* __restrict__ wv,
    const float* __restrict__ wo,
    float* __restrict__ A_T, float* __restrict__ Bp, float* __restrict__ roi,
    __bf16* __restrict__ wAll, __bf16* __restrict__ inT7)
{
    const int b = blockIdx.x, tid = threadIdx.x;
    __shared__ __align__(16) char smem[18432];

    if (b < 48) {
        const int bx = b % 6, by = b / 6;
        const bool isA = bx < 4;
        const bool isRoi = (bx == 5);
        const int ocWg = by * 64;
        const int w = tid >> 6, lane = tid & 63;
        const int q = lane >> 4, l16 = lane & 15;
        __bf16* s_a = (__bf16*)smem;
        __bf16* s_b = s_a + 64 * ROWH;

        f32x4 acc[4];
#pragma unroll
        for (int nt = 0; nt < 4; ++nt) acc[nt] = (f32x4){0.f, 0.f, 0.f, 0.f};

        const int row = tid >> 2, part = tid & 3;
        for (int ch = 0; ch < 32; ++ch) {
            const int c0 = ch * 32;
            __syncthreads();
            if (isA) {
                const int gp = bx * 64 + row;
                bf16x8 val;
#pragma unroll
                for (int j = 0; j < 8; ++j)
                    val[j] = (__bf16)bg[(size_t)(c0 + part * 8 + j) * 256 + gp];
                *(bf16x8*)(&s_a[row * ROWH + part * 8]) = val;
            } else {
                const float* src = actor + (size_t)row * CR + c0 + part * 8;
                bf16x8 val;
#pragma unroll
                for (int j = 0; j < 8; ++j) val[j] = (__bf16)src[j];
                *(bf16x8*)(&s_a[row * ROWH + part * 8]) = val;
            }
            {
                const float* srcb = isRoi
                    ? (wfc1 + (size_t)(ocWg + row) * CR + c0 + part * 8)
                    : (w1 + (size_t)(ocWg + row) * (2 * CR)
                          + (isA ? 0 : CR) + c0 + part * 8);
                bf16x8 vb;
#pragma unroll
                for (int j = 0; j < 8; ++j) vb[j] = (__bf16)srcb[j];
                *(bf16x8*)(&s_b[row * ROWH + part * 8]) = vb;
            }
            __syncthreads();
            const bf16x8 af = *(const bf16x8*)(&s_a[(w * 16 + l16) * ROWH + q * 8]);
#pragma unroll
            for (int nt = 0; nt < 4; ++nt) {
                const bf16x8 bw = *(const bf16x8*)(&s_b[(nt * 16 + l16) * ROWH + q * 8]);
                acc[nt] = __builtin_amdgcn_mfma_f32_16x16x32_bf16(af, bw, acc[nt], 0, 0, 0);
            }
        }
#pragma unroll
        for (int r = 0; r < 4; ++r) {
#pragma unroll
            for (int nt = 0; nt < 4; ++nt) {
                const int mrow = w * 16 + q * 4 + r;
                const int oc = ocWg + nt * 16 + l16;
                if (isA)       A_T[(size_t)(bx * 64 + mrow) * 512 + oc] = acc[nt][r];
                else if (isRoi) roi[(size_t)mrow * 512 + oc] = fmaxf(acc[nt][r], 0.f);
                else           Bp[(size_t)mrow * 512 + oc] = acc[nt][r];
            }
        }
    } else if (b < 4656) {
        const int bid = b - 48;
        const float* src;
        if (bid < 512) src = w2 + (size_t)bid * 4608;
        else if (bid < 2048) {
            const int r = bid - 512;
            const float* bb = r < 512 ? wq : (r < 1024 ? wk : wv);
            src = bb + (size_t)(r & 511) * 4608;
        } else if (bid < 2560) src = wo + (size_t)(bid - 2048) * 4608;
        else if (bid < 4096) {
            const int r = bid - 2560;
            const float* bb = r < 512 ? wq : (r < 1024 ? wk : wv);
            src = bb + WL + (size_t)(r & 511) * 4608;
        } else src = wo + WL + (size_t)(bid - 4096) * 4608;
        float* s = (float*)smem;
        const float4* s4 = (const float4*)src;
        for (int i = tid; i < 1152; i += 256) ((float4*)s)[i] = s4[i];
        __syncthreads();
        for (int u = tid; u < 576; u += 256) {
            const int t = u / 64, o = u - (u / 64) * 64;
            const int swz = (o & 3) ^ ((bid >> 1) & 3);
            const int cbase = o * 8;
            unsigned pack[4];
#pragma unroll
            for (int h = 0; h < 4; ++h) {
                const unsigned short lo = f2bfu(s[(cbase + 2 * h) * 9 + t]);
                const unsigned short hi = f2bfu(s[(cbase + 2 * h + 1) * 9 + t]);
                pack[h] = ((unsigned)hi << 16) | lo;
            }
            const size_t cidx = (size_t)(o >> 2) * 32 + (size_t)swz * 8;
            *(uint4*)(wAll + (size_t)t * TAPSTR + (size_t)bid * 512 + cidx) =
                *(const uint4*)pack;
        }
    } else {
        const int k = b - 4656;            // 0..511
        const int n = k >> 3;
        const int j0 = (k & 7) * 4;
#pragma unroll
        for (int i = 0; i < 4; ++i) {
            const int jj = j0 + i;
            int sp;
            if (jj < 9) sp = jj;
            else if (jj < 18) sp = 63 + jj;
            else { const int t = jj - 18; sp = (1 + (t >> 1)) * 9 + (t & 1) * 8; }
            unsigned* d = (unsigned*)(inT7 + ((size_t)n * 81 + sp) * 512);
            d[tid] = 0u;
        }
    }
}

// ---------- conv2 input: relu(A_T[p][c]+B[n][c]) -> inT2[vn][81][512] -----
__global__ __launch_bounds__(256) void k_prep_in2(
    const float* __restrict__ A_T, const float* __restrict__ B,
    __bf16* __restrict__ dst)
{
    const int vn = blockIdx.x;
    const int n = vn >> 2, quad = vn & 3;
    const int sp0 = blockIdx.y * 27;
    const float b0 = B[n * HIDC + threadIdx.x];
    const float b1 = B[n * HIDC + 256 + threadIdx.x];
    for (int sp = sp0; sp < sp0 + 27; ++sp) {
        const int r = sp / 9, w = sp % 9;
        const int p16 = ((quad >> 1) * 7 + r) * 16 + (quad & 1) * 7 + w;
        __bf16* d = dst + ((size_t)vn * 81 + sp) * 512;
        d[threadIdx.x]       = (__bf16)fmaxf(A_T[p16 * HIDC + threadIdx.x] + b0, 0.f);
        d[256 + threadIdx.x] = (__bf16)fmaxf(A_T[p16 * HIDC + 256 + threadIdx.x] + b1, 0.f);
    }
}

// ---------- GN+relu prep for wo: virt fp32 -> gnT[vn][81][512] bf16 -------
__global__ __launch_bounds__(256) void k_prep_gn(
    const float* __restrict__ virt, const float* __restrict__ statsRaw,
    const float* __restrict__ gamma, const float* __restrict__ beta,
    __bf16* __restrict__ gnT)
{
    const int vn = blockIdx.x;
    const int sp0 = blockIdx.y * 9;
    __shared__ float s_mi[2];
    if (threadIdx.x == 0) {
        const float S = statsRaw[vn * 2], Q = statsRaw[vn * 2 + 1];
        const float mean = S / GNCNT;
        s_mi[0] = mean;
        s_mi[1] = rsqrtf(Q / GNCNT - mean * mean + 1e-5f);
    }
    __syncthreads();
    const float m = s_mi[0], iv = s_mi[1];
    const int c0 = threadIdx.x, c1 = threadIdx.x + 256;
    const float g0 = gamma[c0], g1 = gamma[c1];
    const float b0 = beta[c0],  b1 = beta[c1];
    for (int sp = sp0; sp < sp0 + 9; ++sp) {
        const int rr = sp / 9, cc = sp % 9;
        __bf16* d = gnT + ((size_t)vn * 81 + sp) * 512;
        if (rr >= 1 && rr <= 7 && cc >= 1 && cc <= 7) {
            const int p = (rr - 1) * 7 + (cc - 1);
            const float* src = virt + ((size_t)vn * 49 + p) * 512;
            d[c0] = (__bf16)fmaxf((src[c0] - m) * iv * g0 + b0, 0.f);
            d[c1] = (__bf16)fmaxf((src[c1] - m) * iv * g1 + b1, 0.f);
        } else {
            d[c0] = (__bf16)0.f;
            d[c1] = (__bf16)0.f;
        }
    }
}

// ---------- 3-phase pipelined conv. MODE: 2=conv2, 0=qkv, 1=wo -----------
// OCT: oc tiles (4 -> 64 oc per block; 2 -> 32 oc per block, 2-gll weights)
template<int VN, int MODE, int OCT>
__global__ __launch_bounds__(256, (VN == 4) ? 2 : 3) void k_conv_pipe(
    const __bf16* __restrict__ inT,
    const __bf16* __restrict__ wAll, int ocBaseGl,
    __bf16* __restrict__ outb,
    float* __restrict__ zeroStats, float* __restrict__ gapZero,
    const float* __restrict__ resid, float* __restrict__ outf,
    __bf16* __restrict__ inT7out, float* __restrict__ gapOut)
{
    constexpr int MT = (VN == 4) ? 4 : 2;
    constexpr int SLOTS = VN * 324;                 // 1296 / 648
    constexpr int NSUB = (SLOTS + 255) / 256;       // 6 / 3
    constexpr int SBUF = NSUB * 256;
    constexpr int NI = NSUB / 3;                    // input glls/phase: 2 / 1
    constexpr int WTAP = OCT * 512;                 // halves per tap buffer
    constexpr int SWSZ = 2 * 3 * WTAP + ((OCT == 2) ? 1024 : 0);
    const int tid = threadIdx.x;
    const int w = tid >> 6, lane = tid & 63;
    const int q = lane >> 4, l16 = lane & 15;
    const int vn_l = (VN == 4) ? w : (w & 1);
    const int mh   = (VN == 4) ? 0 : (w >> 1);
    const int vnBase = blockIdx.x * VN;
    const int ocWg = blockIdx.y * (OCT * 16);

    if (zeroStats && blockIdx.x == 0 && blockIdx.y == 0 && tid < 128)
        zeroStats[tid] = 0.f;
    if (gapZero && blockIdx.y == 0 && blockIdx.x < 16) {
        const float4 z = {0.f, 0.f, 0.f, 0.f};
        ((float4*)gapZero)[blockIdx.x * 512 + tid * 2]     = z;
        ((float4*)gapZero)[blockIdx.x * 512 + tid * 2 + 1] = z;
    }

    __shared__ __align__(16) __bf16 s_w[SWSZ];
    __shared__ __align__(16) __bf16 s_in[2 * SBUF * 8];

    unsigned iGo[NSUB];
#pragma unroll
    for (int s = 0; s < NSUB; ++s) {
        int idx = tid + s * 256;
        if (idx > SLOTS - 1) idx = SLOTS - 1;
        const int vnl = idx / 324, rem = idx - vnl * 324;
        const int r = rem >> 2, part = rem & 3;
        iGo[s] = (unsigned)(((vnBase + vnl) * 81 + r) * 512
                            + ((part ^ swzkey(r)) * 8));
    }
    unsigned wGo4 = 0;
    unsigned wGo2[2]; int wJ2[2];
    if constexpr (OCT == 4) {
        wGo4 = (unsigned)((ocBaseGl + ocWg + (tid >> 2)) * 512 + (tid & 3) * 8);
    } else {
#pragma unroll
        for (int k = 0; k < 2; ++k) {
            const int u = tid + k * 256;
            const int jj = (u >> 7) > 2 ? 2 : (u >> 7);
            const int row = (u >> 2) & 31, part = u & 3;
            wGo2[k] = (unsigned)((ocBaseGl + ocWg + row) * 512 + part * 8);
            wJ2[k] = jj;
        }
    }
    const int bOff = l16 * 32 + ((q ^ ((l16 >> 1) & 3)) << 3);

    int aLoc[MT];
#pragma unroll
    for (int mt = 0; mt < MT; ++mt) {
        int p = (mh * MT + mt) * 16 + l16;
        p = p > 48 ? 48 : p;
        aLoc[mt] = (p / 7) * 9 + (p % 7);
    }
    const int vb81 = vn_l * 81;

    f32x4 acc[MT][OCT];
#pragma unroll
    for (int a = 0; a < MT; ++a)
#pragma unroll
        for (int b = 0; b < OCT; ++b) acc[a][b] = (f32x4){0.f, 0.f, 0.f, 0.f};

    auto stageW = [&](int fn, int cc, int wparN) {
        if constexpr (OCT == 4) {
#pragma unroll
            for (int j = 0; j < 3; ++j)
                stage16(wAll + (size_t)(fn * 3 + j) * TAPSTR + wGo4 + cc,
                        (char*)s_w + (size_t)(wparN * 3 + j) * (WTAP * 2)
                                    + (size_t)w * 1024, lane);
        } else {
#pragma unroll
            for (int k = 0; k < 2; ++k) {
                const int ubase = (tid & ~63) + k * 256;
                char* dst;
                if (ubase < 384)
                    dst = (char*)s_w
                        + (size_t)(wparN * 3 + (ubase >> 7)) * (WTAP * 2)
                        + (size_t)(ubase & 127) * 16;
                else
                    dst = (char*)s_w + (size_t)(2 * 3 * WTAP) * 2
                        + (size_t)(ubase - 384) * 16;
                stage16(wAll + (size_t)(fn * 3 + wJ2[k]) * TAPSTR + wGo2[k] + cc,
                        dst, lane);
            }
        }
    };

#pragma unroll
    for (int s = 0; s < NSUB; ++s)
        stage16(inT + iGo[s],
                (char*)s_in + (size_t)(s * 256 + w * 64) * 16, lane);
    stageW(0, 0, 0);
    __syncthreads();

    for (int ch = 0; ch < 16; ++ch) {
        const int c0 = ch * 32;
        const int cur = ch & 1;
        const int nxt = cur ^ 1;
#pragma unroll
        for (int f = 0; f < 3; ++f) {
            const int P = ch * 3 + f;
            const int wpar = P & 1;
            {
                const int fn = (f == 2) ? 0 : (f + 1);
                const int cc = (f == 2) ? (c0 + 32) : c0;
                stageW(fn, cc, wpar ^ 1);
            }
#pragma unroll
            for (int u = 0; u < NI; ++u) {
                const int s = f * NI + u;
                stage16(inT + iGo[s] + c0 + 32,
                        (char*)s_in + (size_t)nxt * (SBUF * 16)
                                    + (size_t)(s * 256 + w * 64) * 16, lane);
            }
            if (f == 0) {
                if constexpr (OCT == 4) {
                    if constexpr (NI == 2) asm volatile("s_waitcnt vmcnt(5)" ::: "memory");
                    else                   asm volatile("s_waitcnt vmcnt(4)" ::: "memory");
                } else {
                    asm volatile("s_waitcnt vmcnt(3)" ::: "memory");
                }
            } else {
                if constexpr (OCT == 4) {
                    if constexpr (NI == 2) asm volatile("s_waitcnt vmcnt(7)" ::: "memory");
                    else                   asm volatile("s_waitcnt vmcnt(5)" ::: "memory");
                } else {
                    asm volatile("s_waitcnt vmcnt(4)" ::: "memory");
                }
            }
            __builtin_amdgcn_sched_barrier(0);
            __builtin_amdgcn_s_barrier();
            __builtin_amdgcn_sched_barrier(0);
#pragma unroll
            for (int j = 0; j < 3; ++j) {
                const int DT = f * 9 + j;
                bf16x8 bw[OCT];
#pragma unroll
                for (int nt = 0; nt < OCT; ++nt)
                    bw[nt] = *(const bf16x8*)(
                        &s_w[(wpar * 3 + j) * WTAP + nt * 512 + bOff]);
                bf16x8 af[MT];
#pragma unroll
                for (int mt = 0; mt < MT; ++mt) {
                    const int rl = aLoc[mt] + DT;
                    const int col = (q ^ swzkey(rl)) << 3;
                    af[mt] = *(const bf16x8*)(
                        &s_in[cur * (SBUF * 8) + (vb81 + rl) * 32 + col]);
                }
#pragma unroll
                for (int mt = 0; mt < MT; ++mt)
#pragma unroll
                    for (int nt = 0; nt < OCT; ++nt)
                        acc[mt][nt] = __builtin_amdgcn_mfma_f32_16x16x32_bf16(
                            af[mt], bw[nt], acc[mt][nt], 0, 0, 0);
            }
            __builtin_amdgcn_sched_barrier(0);
            __builtin_amdgcn_s_barrier();
        }
    }

    const int vn = vnBase + vn_l;
    float gsum[OCT];
#pragma unroll
    for (int nt = 0; nt < OCT; ++nt) gsum[nt] = 0.f;
#pragma unroll
    for (int mt = 0; mt < MT; ++mt) {
#pragma unroll
        for (int r = 0; r < 4; ++r) {
            const int p = (mh * MT + mt) * 16 + q * 4 + r;
            if (p >= 49) continue;
#pragma unroll
            for (int nt = 0; nt < OCT; ++nt) {
                const int oc = ocWg + nt * 16 + l16;
                const float v = acc[mt][nt][r];
                if constexpr (MODE == 2) {
                    const int n = vn >> 2, quad = vn & 3;
                    const int p14 = ((quad >> 1) * 7 + p / 7) * 14 + (quad & 1) * 7 + p % 7;
                    outb[((size_t)n * 196 + p14) * 512 + oc] = (__bf16)fmaxf(v, 0.f);
                } else if constexpr (MODE == 1) {
                    const size_t addr = ((size_t)vn * 49 + p) * 512 + oc;
                    const float res = v + resid[addr];
                    if (!gapOut) outf[addr] = res;
                    gsum[nt] += res;
                    if (inT7out) {
                        const int sp = (p / 7 + 1) * 9 + (p % 7 + 1);
                        inT7out[((size_t)vn * 81 + sp) * 512 + oc] = (__bf16)res;
                    }
                } else {
                    const int conv = oc >> 9;
                    outb[(size_t)conv * PLANE + ((size_t)p * 64 + vn) * 512 + (oc & 511)]
                        = (__bf16)v;
                }
            }
        }
    }
    if constexpr (MODE == 1) {
        if (gapOut) {
#pragma unroll
            for (int nt = 0; nt < OCT; ++nt)
                atomicAdd(gapOut + (size_t)vn * 512 + ocWg + nt * 16 + l16, gsum[nt]);
        }
    }
}

// ---------- fused maxpool + bf16 pack (interior) + fp32 residual ----------
__global__ __launch_bounds__(256) void k_pool_prep(
    const __bf16* __restrict__ x2, __bf16* __restrict__ inT7,
    float* __restrict__ xA)
{
    const int b = blockIdx.x;
    const int n = b / 49, p = b % 49;
    const int i = p / 7, j = p % 7;
    const int sp = (i + 1) * 9 + (j + 1);
#pragma unroll
    for (int k = 0; k < 2; ++k) {
        const int c = threadIdx.x + k * 256;
        float mx = -1e30f;
#pragma unroll
        for (int di = -1; di <= 1; ++di) {
            const int rr = 2 * i + di;
            if (rr < 0 || rr >= 14) continue;
#pragma unroll
            for (int dj = -1; dj <= 1; ++dj) {
                const int cc = 2 * j + dj;
                if (cc < 0 || cc >= 14) continue;
                mx = fmaxf(mx, (float)x2[((size_t)n * 196 + rr * 14 + cc) * 512 + c]);
            }
        }
        inT7[((size_t)n * 81 + sp) * 512 + c] = (__bf16)mx;
        xA[((size_t)n * 49 + p) * 512 + c] = mx;
    }
}

// ---------- fused attention + GN partial stats ----------
__global__ __launch_bounds__(256) void k_attvirt(
    const __bf16* __restrict__ qT, const __bf16* __restrict__ kT,
    const __bf16* __restrict__ vT, float* __restrict__ virt,
    float* __restrict__ statsRaw)
{
    const int p = blockIdx.y;
    const int w = threadIdx.x >> 6, m = threadIdx.x & 63;
    const int n = blockIdx.x * 4 + w;
    __shared__ float s_q[4][HIDC];
    __shared__ float s_a[4][64];
    {
        const uint4 v = ((const uint4*)(qT + ((size_t)p * 64 + n) * HIDC))[m];
        const unsigned* u = (const unsigned*)&v;
#pragma unroll
        for (int j = 0; j < 4; ++j) {
            s_q[w][m * 8 + 2 * j]     = bf2f((unsigned short)(u[j] & 0xffff));
            s_q[w][m * 8 + 2 * j + 1] = bf2f((unsigned short)(u[j] >> 16));
        }
    }
    __syncthreads();
    const uint4* krow = (const uint4*)(kT + ((size_t)p * 64 + m) * HIDC);
    float acc0 = 0.f, acc1 = 0.f;
    for (int i = 0; i < 64; ++i) {
        const uint4 v = krow[i];
        const unsigned* u = (const unsigned*)&v;
#pragma unroll
        for (int j = 0; j < 2; ++j) {
            acc0 = fmaf(s_q[w][i * 8 + 2 * j],     bf2f((unsigned short)(u[j] & 0xffff)), acc0);
            acc0 = fmaf(s_q[w][i * 8 + 2 * j + 1], bf2f((unsigned short)(u[j] >> 16)),    acc0);
        }
#pragma unroll
        for (int j = 2; j < 4; ++j) {
            acc1 = fmaf(s_q[w][i * 8 + 2 * j],     bf2f((unsigned short)(u[j] & 0xffff)), acc1);
            acc1 = fmaf(s_q[w][i * 8 + 2 * j + 1], bf2f((unsigned short)(u[j] >> 16)),    acc1);
        }
    }
    float acc = (acc0 + acc1) * 0.044194173824159216f;
    float mx = acc;
#pragma unroll
    for (int off = 32; off; off >>= 1) mx = fmaxf(mx, __shfl_xor(mx, off));
    const float e = expf(acc - mx);
    float s = e;
#pragma unroll
    for (int off = 32; off; off >>= 1) s += __shfl_xor(s, off);
    s_a[w][m] = e / s;
    __syncthreads();
    const int c0 = m * 8;
    float av[8];
#pragma unroll
    for (int j = 0; j < 8; ++j) av[j] = 0.f;
    for (int mm = 0; mm < 64; ++mm) {
        const float a = s_a[w][mm];
        const uint4 v = *(const uint4*)(vT + ((size_t)p * 64 + mm) * HIDC + c0);
        const unsigned* u = (const unsigned*)&v;
#pragma unroll
        for (int j = 0; j < 4; ++j) {
            av[2 * j]     = fmaf(a, bf2f((unsigned short)(u[j] & 0xffff)), av[2 * j]);
            av[2 * j + 1] = fmaf(a, bf2f((unsigned short)(u[j] >> 16)),    av[2 * j + 1]);
        }
    }
    float* o = virt + ((size_t)n * 49 + p) * 512 + c0;
    float ps = 0.f, pq = 0.f;
#pragma unroll
    for (int j = 0; j < 8; ++j) {
        o[j] = av[j];
        ps += av[j];
        pq = fmaf(av[j], av[j], pq);
    }
#pragma unroll
    for (int off = 32; off; off >>= 1) {
        ps += __shfl_xor(ps, off);
        pq += __shfl_xor(pq, off);
    }
    if (m == 0) {
        atomicAdd(statsRaw + n * 2, ps);
        atomicAdd(statsRaw + n * 2 + 1, pq);
    }
}

// ---------- final fc: out[n][k] = [roi | gap/49] . wfc2[k] ----------
__global__ __launch_bounds__(256) void k_final(
    const float* __restrict__ roi, const float* __restrict__ gap,
    const float* __restrict__ wfc2, float* __restrict__ out)
{
    const int n = blockIdx.x, tid = threadIdx.x;
    __shared__ float s[1024];
    s[tid]       = roi[(size_t)n * 512 + tid];
    s[tid + 256] = roi[(size_t)n * 512 + 256 + tid];
    s[tid + 512] = gap[(size_t)n * 512 + tid] * (1.f / 49.f);
    s[tid + 768] = gap[(size_t)n * 512 + 256 + tid] * (1.f / 49.f);
    __syncthreads();
    if (tid < 240) {
        const int k = tid >> 2, part = tid & 3;
        const float4* w4 = (const float4*)(wfc2 + (size_t)k * 1024 + part * 256);
        const float4* s4 = (const float4*)(s + part * 256);
        float a0 = 0.f, a1 = 0.f, a2 = 0.f, a3 = 0.f;
        for (int i = 0; i < 64; ++i) {
            const float4 wv = w4[i], sv = s4[i];
            a0 = fmaf(wv.x, sv.x, a0); a1 = fmaf(wv.y, sv.y, a1);
            a2 = fmaf(wv.z, sv.z, a2); a3 = fmaf(wv.w, sv.w, a3);
        }
        float acc = (a0 + a1) + (a2 + a3);
        acc += __shfl_xor(acc, 1);
        acc += __shfl_xor(acc, 2);
        if (part == 0) out[n * NCLS + k] = acc;
    }
}

// ---------------------------------------------------------------------------
extern "C" void kernel_launch(void* const* d_in, const int* in_sizes, int n_in,
                              void* d_out, int out_size, void* d_ws, size_t ws_size,
                              hipStream_t stream) {
    const float* bg    = (const float*)d_in[0];
    const float* actor = (const float*)d_in[1];
    const float* w1    = (const float*)d_in[2];
    const float* w2    = (const float*)d_in[3];
    const float* wq    = (const float*)d_in[4];
    const float* wk    = (const float*)d_in[5];
    const float* wv    = (const float*)d_in[6];
    const float* wo    = (const float*)d_in[7];
    const float* gamma = (const float*)d_in[8];
    const float* beta  = (const float*)d_in[9];
    const float* wfc1  = (const float*)d_in[10];
    const float* wfc2  = (const float*)d_in[11];
    float* out = (float*)d_out;
    float* ws  = (float*)d_ws;

    // ---- fp32 regions ----
    float* A_T   = ws;                        // 131,072
    float* Bp    = A_T + 131072;              // 32,768
    float* xA    = Bp + 32768;                // PLANE
    float* xB    = xA + PLANE;                // PLANE
    float* stats = xB + PLANE;                // 128
    float* roi   = stats + 128;               // 32,768
    float* gap   = roi + 32768;               // 32,768
    float* fend  = gap + 32768;
    // ---- bf16 regions ----
    __bf16* x2h  = (__bf16*)fend;             // 64*196*512 = 6,422,528 halves
    float*  virt = (float*)x2h;               // aliases x2h (dead after pool)
    __bf16* inT2 = x2h + 6422528;             // 256*81*512 = 10,616,832
    __bf16* qkvT = inT2;                      // aliases inT2 (dead after conv2)
    __bf16* inT7 = inT2 + 10616832;           // 64*81*512  = 2,654,208
    __bf16* wAll = inT7 + 2654208;            // 9*4608*512 = 21,233,664
    __bf16* gnT  = wAll + (size_t)9 * OCALL * 512 + 262144;

    // 1: ab GEMM + weight transpose + inT7 borders (merged)
    k_mega<<<5168, 256, 0, stream>>>(bg, actor, w1, wfc1, w2, wq, wk, wv, wo,
                                     A_T, Bp, roi, wAll, inT7);
    // 2: conv2 input planes
    k_prep_in2<<<dim3(256, 3), 256, 0, stream>>>(A_T, Bp, inT2);
    // 3: conv2 — 3-phase pipelined, VN4/OCT4 (64,8)=512 wgs = 2/CU
    k_conv_pipe<4, 2, 4><<<dim3(64, 8), 256, 0, stream>>>(
        inT2, wAll, 0, x2h, nullptr, nullptr,
        nullptr, nullptr, nullptr, nullptr);
    // 4: pool + pack + residual
    k_pool_prep<<<64 * 49, 256, 0, stream>>>(x2h, inT7, xA);

    float* xin = xA;
    float* xout = xB;
    for (int d = 0; d < 2; ++d) {
        // 5/8: fused qkv — 3-phase pipelined, VN2/OCT4 (32,24)=768 wgs = 3/CU
        k_conv_pipe<2, 0, 4><<<dim3(32, 24), 256, 0, stream>>>(
            inT7, wAll, 512 + d * 2048, qkvT, stats,
            d == 1 ? gap : nullptr,
            nullptr, nullptr, nullptr, nullptr);
        // 6/9: attention + GN partial stats
        k_attvirt<<<dim3(16, 49), 256, 0, stream>>>(
            qkvT, qkvT + PLANE, qkvT + 2 * PLANE, virt, stats);
        // 6.5/9.5: GN+relu materialization for wo pipe
        k_prep_gn<<<dim3(64, 9), 256, 0, stream>>>(
            virt, stats, gamma + d * HIDC, beta + d * HIDC, gnT);
        // 7/10: wo conv — VN2/OCT2 oc-split: (32,16)=512 wgs = 2/CU
        k_conv_pipe<2, 1, 2><<<dim3(32, 16), 256, 0, stream>>>(
            gnT, wAll, 2048 + d * 2048, nullptr, nullptr, nullptr,
            xin, xout, d == 0 ? inT7 : nullptr, d == 1 ? gap : nullptr);
        float* t = xin; xin = xout; xout = t;
    }
    // 11: final fc from roi + fused gap
    k_final<<<64, 256, 0, stream>>>(roi, gap, wfc2, out);
}

// Round 22
// 539.702 us; speedup vs baseline: 1.5427x; 1.0566x over previous
//
#include <hip/hip_runtime.h>
#include <math.h>

// ---------------------------------------------------------------------------
// ACARHead — R30: R29 (570us best) + split-K ab GEMM in k_mega.
// k_mega was 70us with NOTHING busy (Mfma 0.2%, VALU 4%, HBM 17%): the 48
// ab blocks (19% fill, 32 serial 2-phase chunks, scalar transposed-bg
// loads) are a latency straggler tail. Fix: ab -> 192 blocks (4 K-quarters
// x 48), each runs 8 chunks and atomicAdds fp32 partials into A_T/Bp/roi.
// Accumulators zeroed by ONE hipMemsetAsync (A_T/Bp/roi made adjacent in
// ws; memset is graph-capture-safe). roi's relu moves to k_final's load.
// Everything else byte-identical to R29 (conv pipes, wo oc-split, prep_gn).
// ---------------------------------------------------------------------------

typedef __bf16 bf16x8 __attribute__((ext_vector_type(8)));
typedef float  f32x4  __attribute__((ext_vector_type(4)));

#define NROI 64
#define CR   1024
#define HIDC 512
#define NCLS 60
#define PLANE (NROI * HIDC * 49)        // 1,605,632
#define ROWH 40
#define OCALL 4608
#define TAPSTR ((size_t)OCALL * 512)
#define WL (HIDC * HIDC * 9)
#define GNCNT 25088.0f                   // 512*49

#if defined(__has_builtin)
#  if __has_builtin(__builtin_amdgcn_global_load_lds)
#    define HAVE_GLL 1
#  endif
#endif

__device__ __forceinline__ void stage16(const void* g, void* lds_base, int lane) {
#ifdef HAVE_GLL
    __builtin_amdgcn_global_load_lds(
        (const __attribute__((address_space(1))) unsigned int*)g,
        (__attribute__((address_space(3))) unsigned int*)lds_base, 16, 0, 0);
#else
    *(uint4*)((char*)lds_base + lane * 16) = *(const uint4*)g;
#endif
}

__device__ __forceinline__ float bf2f(unsigned short h) {
    union { unsigned u; float f; } x; x.u = (unsigned)h << 16; return x.f;
}

__device__ __forceinline__ unsigned short f2bfu(float f) {
    return __builtin_bit_cast(unsigned short, (__bf16)f);
}

// bank-spread swizzle key for input rows (R23, kept)
__device__ __forceinline__ int swzkey(int r) {
    return (r & 3) ^ ((r >> 2) & 3);
}

// ---------- mega prologue: split-K ab GEMM | weight transpose | borders ----
// [0,192): ab split-K (atomicAdd into zeroed A_T/Bp/roi);
// [192,4800): wAll row; [4800,5312): inT7 borders.
__global__ __launch_bounds__(256) void k_mega(
    const float* __restrict__ bg, const float* __restrict__ actor,
    const float* __restrict__ w1, const float* __restrict__ wfc1,
    const float* __restrict__ w2, const float* __restrict__ wq,
    const float* __restrict__ wk, const float* __restrict__ wv,
    const float* __restrict__ wo,
    float* __restrict__ A_T, float* __restrict__ Bp, float* __restrict__ roi,
    __bf16* __restrict__ wAll, __bf16* __restrict__ inT7)
{
    const int b = blockIdx.x, tid = threadIdx.x;
    __shared__ __align__(16) char smem[18432];

    if (b < 192) {
        // ---------------- ab GEMM, split-K x4 ----------------
        const int sub = b & 3;                 // K-quarter: chunks [8s,8s+8)
        const int bb = b >> 2;
        const int bx = bb % 6, by = bb / 6;
        const bool isA = bx < 4;
        const bool isRoi = (bx == 5);
        const int ocWg = by * 64;
        const int w = tid >> 6, lane = tid & 63;
        const int q = lane >> 4, l16 = lane & 15;
        __bf16* s_a = (__bf16*)smem;
        __bf16* s_b = s_a + 64 * ROWH;

        f32x4 acc[4];
#pragma unroll
        for (int nt = 0; nt < 4; ++nt) acc[nt] = (f32x4){0.f, 0.f, 0.f, 0.f};

        const int row = tid >> 2, part = tid & 3;
        for (int ch = sub * 8; ch < sub * 8 + 8; ++ch) {
            const int c0 = ch * 32;
            __syncthreads();
            if (isA) {
                const int gp = bx * 64 + row;
                bf16x8 val;
#pragma unroll
                for (int j = 0; j < 8; ++j)
                    val[j] = (__bf16)bg[(size_t)(c0 + part * 8 + j) * 256 + gp];
                *(bf16x8*)(&s_a[row * ROWH + part * 8]) = val;
            } else {
                const float* src = actor + (size_t)row * CR + c0 + part * 8;
                bf16x8 val;
#pragma unroll
                for (int j = 0; j < 8; ++j) val[j] = (__bf16)src[j];
                *(bf16x8*)(&s_a[row * ROWH + part * 8]) = val;
            }
            {
                const float* srcb = isRoi
                    ? (wfc1 + (size_t)(ocWg + row) * CR + c0 + part * 8)
                    : (w1 + (size_t)(ocWg + row) * (2 * CR)
                          + (isA ? 0 : CR) + c0 + part * 8);
                bf16x8 vb;
#pragma unroll
                for (int j = 0; j < 8; ++j) vb[j] = (__bf16)srcb[j];
                *(bf16x8*)(&s_b[row * ROWH + part * 8]) = vb;
            }
            __syncthreads();
            const bf16x8 af = *(const bf16x8*)(&s_a[(w * 16 + l16) * ROWH + q * 8]);
#pragma unroll
            for (int nt = 0; nt < 4; ++nt) {
                const bf16x8 bw = *(const bf16x8*)(&s_b[(nt * 16 + l16) * ROWH + q * 8]);
                acc[nt] = __builtin_amdgcn_mfma_f32_16x16x32_bf16(af, bw, acc[nt], 0, 0, 0);
            }
        }
        // split-K epilogue: accumulate partials (roi relu moved to k_final)
#pragma unroll
        for (int r = 0; r < 4; ++r) {
#pragma unroll
            for (int nt = 0; nt < 4; ++nt) {
                const int mrow = w * 16 + q * 4 + r;
                const int oc = ocWg + nt * 16 + l16;
                if (isA)
                    atomicAdd(&A_T[(size_t)(bx * 64 + mrow) * 512 + oc], acc[nt][r]);
                else if (isRoi)
                    atomicAdd(&roi[(size_t)mrow * 512 + oc], acc[nt][r]);
                else
                    atomicAdd(&Bp[(size_t)mrow * 512 + oc], acc[nt][r]);
            }
        }
    } else if (b < 4800) {
        // ---------------- weight transpose ----------------
        const int bid = b - 192;
        const float* src;
        if (bid < 512) src = w2 + (size_t)bid * 4608;
        else if (bid < 2048) {
            const int r = bid - 512;
            const float* bb = r < 512 ? wq : (r < 1024 ? wk : wv);
            src = bb + (size_t)(r & 511) * 4608;
        } else if (bid < 2560) src = wo + (size_t)(bid - 2048) * 4608;
        else if (bid < 4096) {
            const int r = bid - 2560;
            const float* bb = r < 512 ? wq : (r < 1024 ? wk : wv);
            src = bb + WL + (size_t)(r & 511) * 4608;
        } else src = wo + WL + (size_t)(bid - 4096) * 4608;
        float* s = (float*)smem;
        const float4* s4 = (const float4*)src;
        for (int i = tid; i < 1152; i += 256) ((float4*)s)[i] = s4[i];
        __syncthreads();
        for (int u = tid; u < 576; u += 256) {
            const int t = u / 64, o = u - (u / 64) * 64;
            const int swz = (o & 3) ^ ((bid >> 1) & 3);
            const int cbase = o * 8;
            unsigned pack[4];
#pragma unroll
            for (int h = 0; h < 4; ++h) {
                const unsigned short lo = f2bfu(s[(cbase + 2 * h) * 9 + t]);
                const unsigned short hi = f2bfu(s[(cbase + 2 * h + 1) * 9 + t]);
                pack[h] = ((unsigned)hi << 16) | lo;
            }
            const size_t cidx = (size_t)(o >> 2) * 32 + (size_t)swz * 8;
            *(uint4*)(wAll + (size_t)t * TAPSTR + (size_t)bid * 512 + cidx) =
                *(const uint4*)pack;
        }
    } else {
        // ---------------- inT7 border zeros ----------------
        const int k = b - 4800;            // 0..511
        const int n = k >> 3;
        const int j0 = (k & 7) * 4;
#pragma unroll
        for (int i = 0; i < 4; ++i) {
            const int jj = j0 + i;
            int sp;
            if (jj < 9) sp = jj;
            else if (jj < 18) sp = 63 + jj;
            else { const int t = jj - 18; sp = (1 + (t >> 1)) * 9 + (t & 1) * 8; }
            unsigned* d = (unsigned*)(inT7 + ((size_t)n * 81 + sp) * 512);
            d[tid] = 0u;
        }
    }
}

// ---------- conv2 input: relu(A_T[p][c]+B[n][c]) -> inT2[vn][81][512] -----
__global__ __launch_bounds__(256) void k_prep_in2(
    const float* __restrict__ A_T, const float* __restrict__ B,
    __bf16* __restrict__ dst)
{
    const int vn = blockIdx.x;
    const int n = vn >> 2, quad = vn & 3;
    const int sp0 = blockIdx.y * 27;
    const float b0 = B[n * HIDC + threadIdx.x];
    const float b1 = B[n * HIDC + 256 + threadIdx.x];
    for (int sp = sp0; sp < sp0 + 27; ++sp) {
        const int r = sp / 9, w = sp % 9;
        const int p16 = ((quad >> 1) * 7 + r) * 16 + (quad & 1) * 7 + w;
        __bf16* d = dst + ((size_t)vn * 81 + sp) * 512;
        d[threadIdx.x]       = (__bf16)fmaxf(A_T[p16 * HIDC + threadIdx.x] + b0, 0.f);
        d[256 + threadIdx.x] = (__bf16)fmaxf(A_T[p16 * HIDC + 256 + threadIdx.x] + b1, 0.f);
    }
}

// ---------- GN+relu prep for wo: virt fp32 -> gnT[vn][81][512] bf16 -------
__global__ __launch_bounds__(256) void k_prep_gn(
    const float* __restrict__ virt, const float* __restrict__ statsRaw,
    const float* __restrict__ gamma, const float* __restrict__ beta,
    __bf16* __restrict__ gnT)
{
    const int vn = blockIdx.x;
    const int sp0 = blockIdx.y * 9;
    __shared__ float s_mi[2];
    if (threadIdx.x == 0) {
        const float S = statsRaw[vn * 2], Q = statsRaw[vn * 2 + 1];
        const float mean = S / GNCNT;
        s_mi[0] = mean;
        s_mi[1] = rsqrtf(Q / GNCNT - mean * mean + 1e-5f);
    }
    __syncthreads();
    const float m = s_mi[0], iv = s_mi[1];
    const int c0 = threadIdx.x, c1 = threadIdx.x + 256;
    const float g0 = gamma[c0], g1 = gamma[c1];
    const float b0 = beta[c0],  b1 = beta[c1];
    for (int sp = sp0; sp < sp0 + 9; ++sp) {
        const int rr = sp / 9, cc = sp % 9;
        __bf16* d = gnT + ((size_t)vn * 81 + sp) * 512;
        if (rr >= 1 && rr <= 7 && cc >= 1 && cc <= 7) {
            const int p = (rr - 1) * 7 + (cc - 1);
            const float* src = virt + ((size_t)vn * 49 + p) * 512;
            d[c0] = (__bf16)fmaxf((src[c0] - m) * iv * g0 + b0, 0.f);
            d[c1] = (__bf16)fmaxf((src[c1] - m) * iv * g1 + b1, 0.f);
        } else {
            d[c0] = (__bf16)0.f;
            d[c1] = (__bf16)0.f;
        }
    }
}

// ---------- 3-phase pipelined conv. MODE: 2=conv2, 0=qkv, 1=wo -----------
// OCT: oc tiles (4 -> 64 oc per block; 2 -> 32 oc per block, 2-gll weights)
template<int VN, int MODE, int OCT>
__global__ __launch_bounds__(256, (VN == 4) ? 2 : 3) void k_conv_pipe(
    const __bf16* __restrict__ inT,
    const __bf16* __restrict__ wAll, int ocBaseGl,
    __bf16* __restrict__ outb,
    float* __restrict__ zeroStats, float* __restrict__ gapZero,
    const float* __restrict__ resid, float* __restrict__ outf,
    __bf16* __restrict__ inT7out, float* __restrict__ gapOut)
{
    constexpr int MT = (VN == 4) ? 4 : 2;
    constexpr int SLOTS = VN * 324;                 // 1296 / 648
    constexpr int NSUB = (SLOTS + 255) / 256;       // 6 / 3
    constexpr int SBUF = NSUB * 256;
    constexpr int NI = NSUB / 3;                    // input glls/phase: 2 / 1
    constexpr int WTAP = OCT * 512;                 // halves per tap buffer
    constexpr int SWSZ = 2 * 3 * WTAP + ((OCT == 2) ? 1024 : 0);
    const int tid = threadIdx.x;
    const int w = tid >> 6, lane = tid & 63;
    const int q = lane >> 4, l16 = lane & 15;
    const int vn_l = (VN == 4) ? w : (w & 1);
    const int mh   = (VN == 4) ? 0 : (w >> 1);
    const int vnBase = blockIdx.x * VN;
    const int ocWg = blockIdx.y * (OCT * 16);

    if (zeroStats && blockIdx.x == 0 && blockIdx.y == 0 && tid < 128)
        zeroStats[tid] = 0.f;
    if (gapZero && blockIdx.y == 0 && blockIdx.x < 16) {
        const float4 z = {0.f, 0.f, 0.f, 0.f};
        ((float4*)gapZero)[blockIdx.x * 512 + tid * 2]     = z;
        ((float4*)gapZero)[blockIdx.x * 512 + tid * 2 + 1] = z;
    }

    __shared__ __align__(16) __bf16 s_w[SWSZ];
    __shared__ __align__(16) __bf16 s_in[2 * SBUF * 8];

    unsigned iGo[NSUB];
#pragma unroll
    for (int s = 0; s < NSUB; ++s) {
        int idx = tid + s * 256;
        if (idx > SLOTS - 1) idx = SLOTS - 1;
        const int vnl = idx / 324, rem = idx - vnl * 324;
        const int r = rem >> 2, part = rem & 3;
        iGo[s] = (unsigned)(((vnBase + vnl) * 81 + r) * 512
                            + ((part ^ swzkey(r)) * 8));
    }
    unsigned wGo4 = 0;
    unsigned wGo2[2]; int wJ2[2];
    if constexpr (OCT == 4) {
        wGo4 = (unsigned)((ocBaseGl + ocWg + (tid >> 2)) * 512 + (tid & 3) * 8);
    } else {
#pragma unroll
        for (int k = 0; k < 2; ++k) {
            const int u = tid + k * 256;
            const int jj = (u >> 7) > 2 ? 2 : (u >> 7);
            const int row = (u >> 2) & 31, part = u & 3;
            wGo2[k] = (unsigned)((ocBaseGl + ocWg + row) * 512 + part * 8);
            wJ2[k] = jj;
        }
    }
    const int bOff = l16 * 32 + ((q ^ ((l16 >> 1) & 3)) << 3);

    int aLoc[MT];
#pragma unroll
    for (int mt = 0; mt < MT; ++mt) {
        int p = (mh * MT + mt) * 16 + l16;
        p = p > 48 ? 48 : p;
        aLoc[mt] = (p / 7) * 9 + (p % 7);
    }
    const int vb81 = vn_l * 81;

    f32x4 acc[MT][OCT];
#pragma unroll
    for (int a = 0; a < MT; ++a)
#pragma unroll
        for (int b = 0; b < OCT; ++b) acc[a][b] = (f32x4){0.f, 0.f, 0.f, 0.f};

    auto stageW = [&](int fn, int cc, int wparN) {
        if constexpr (OCT == 4) {
#pragma unroll
            for (int j = 0; j < 3; ++j)
                stage16(wAll + (size_t)(fn * 3 + j) * TAPSTR + wGo4 + cc,
                        (char*)s_w + (size_t)(wparN * 3 + j) * (WTAP * 2)
                                    + (size_t)w * 1024, lane);
        } else {
#pragma unroll
            for (int k = 0; k < 2; ++k) {
                const int ubase = (tid & ~63) + k * 256;
                char* dst;
                if (ubase < 384)
                    dst = (char*)s_w
                        + (size_t)(wparN * 3 + (ubase >> 7)) * (WTAP * 2)
                        + (size_t)(ubase & 127) * 16;
                else
                    dst = (char*)s_w + (size_t)(2 * 3 * WTAP) * 2
                        + (size_t)(ubase - 384) * 16;
                stage16(wAll + (size_t)(fn * 3 + wJ2[k]) * TAPSTR + wGo2[k] + cc,
                        dst, lane);
            }
        }
    };

#pragma unroll
    for (int s = 0; s < NSUB; ++s)
        stage16(inT + iGo[s],
                (char*)s_in + (size_t)(s * 256 + w * 64) * 16, lane);
    stageW(0, 0, 0);
    __syncthreads();

    for (int ch = 0; ch < 16; ++ch) {
        const int c0 = ch * 32;
        const int cur = ch & 1;
        const int nxt = cur ^ 1;
#pragma unroll
        for (int f = 0; f < 3; ++f) {
            const int P = ch * 3 + f;
            const int wpar = P & 1;
            {
                const int fn = (f == 2) ? 0 : (f + 1);
                const int cc = (f == 2) ? (c0 + 32) : c0;
                stageW(fn, cc, wpar ^ 1);
            }
#pragma unroll
            for (int u = 0; u < NI; ++u) {
                const int s = f * NI + u;
                stage16(inT + iGo[s] + c0 + 32,
                        (char*)s_in + (size_t)nxt * (SBUF * 16)
                                    + (size_t)(s * 256 + w * 64) * 16, lane);
            }
            if (f == 0) {
                if constexpr (OCT == 4) {
                    if constexpr (NI == 2) asm volatile("s_waitcnt vmcnt(5)" ::: "memory");
                    else                   asm volatile("s_waitcnt vmcnt(4)" ::: "memory");
                } else {
                    asm volatile("s_waitcnt vmcnt(3)" ::: "memory");
                }
            } else {
                if constexpr (OCT == 4) {
                    if constexpr (NI == 2) asm volatile("s_waitcnt vmcnt(7)" ::: "memory");
                    else                   asm volatile("s_waitcnt vmcnt(5)" ::: "memory");
                } else {
                    asm volatile("s_waitcnt vmcnt(4)" ::: "memory");
                }
            }
            __builtin_amdgcn_sched_barrier(0);
            __builtin_amdgcn_s_barrier();
            __builtin_amdgcn_sched_barrier(0);
#pragma unroll
            for (int j = 0; j < 3; ++j) {
                const int DT = f * 9 + j;
                bf16x8 bw[OCT];
#pragma unroll
                for (int nt = 0; nt < OCT; ++nt)
                    bw[nt] = *(const bf16x8*)(
                        &s_w[(wpar * 3 + j) * WTAP + nt * 512 + bOff]);
                bf16x8 af[MT];
#pragma unroll
                for (int mt = 0; mt < MT; ++mt) {
                    const int rl = aLoc[mt] + DT;
                    const int col = (q ^ swzkey(rl)) << 3;
                    af[mt] = *(const bf16x8*)(
                        &s_in[cur * (SBUF * 8) + (vb81 + rl) * 32 + col]);
                }
#pragma unroll
                for (int mt = 0; mt < MT; ++mt)
#pragma unroll
                    for (int nt = 0; nt < OCT; ++nt)
                        acc[mt][nt] = __builtin_amdgcn_mfma_f32_16x16x32_bf16(
                            af[mt], bw[nt], acc[mt][nt], 0, 0, 0);
            }
            __builtin_amdgcn_sched_barrier(0);
            __builtin_amdgcn_s_barrier();
        }
    }

    const int vn = vnBase + vn_l;
    float gsum[OCT];
#pragma unroll
    for (int nt = 0; nt < OCT; ++nt) gsum[nt] = 0.f;
#pragma unroll
    for (int mt = 0; mt < MT; ++mt) {
#pragma unroll
        for (int r = 0; r < 4; ++r) {
            const int p = (mh * MT + mt) * 16 + q * 4 + r;
            if (p >= 49) continue;
#pragma unroll
            for (int nt = 0; nt < OCT; ++nt) {
                const int oc = ocWg + nt * 16 + l16;
                const float v = acc[mt][nt][r];
                if constexpr (MODE == 2) {
                    const int n = vn >> 2, quad = vn & 3;
                    const int p14 = ((quad >> 1) * 7 + p / 7) * 14 + (quad & 1) * 7 + p % 7;
                    outb[((size_t)n * 196 + p14) * 512 + oc] = (__bf16)fmaxf(v, 0.f);
                } else if constexpr (MODE == 1) {
                    const size_t addr = ((size_t)vn * 49 + p) * 512 + oc;
                    const float res = v + resid[addr];
                    if (!gapOut) outf[addr] = res;
                    gsum[nt] += res;
                    if (inT7out) {
                        const int sp = (p / 7 + 1) * 9 + (p % 7 + 1);
                        inT7out[((size_t)vn * 81 + sp) * 512 + oc] = (__bf16)res;
                    }
                } else {
                    const int conv = oc >> 9;
                    outb[(size_t)conv * PLANE + ((size_t)p * 64 + vn) * 512 + (oc & 511)]
                        = (__bf16)v;
                }
            }
        }
    }
    if constexpr (MODE == 1) {
        if (gapOut) {
#pragma unroll
            for (int nt = 0; nt < OCT; ++nt)
                atomicAdd(gapOut + (size_t)vn * 512 + ocWg + nt * 16 + l16, gsum[nt]);
        }
    }
}

// ---------- fused maxpool + bf16 pack (interior) + fp32 residual ----------
__global__ __launch_bounds__(256) void k_pool_prep(
    const __bf16* __restrict__ x2, __bf16* __restrict__ inT7,
    float* __restrict__ xA)
{
    const int b = blockIdx.x;
    const int n = b / 49, p = b % 49;
    const int i = p / 7, j = p % 7;
    const int sp = (i + 1) * 9 + (j + 1);
#pragma unroll
    for (int k = 0; k < 2; ++k) {
        const int c = threadIdx.x + k * 256;
        float mx = -1e30f;
#pragma unroll
        for (int di = -1; di <= 1; ++di) {
            const int rr = 2 * i + di;
            if (rr < 0 || rr >= 14) continue;
#pragma unroll
            for (int dj = -1; dj <= 1; ++dj) {
                const int cc = 2 * j + dj;
                if (cc < 0 || cc >= 14) continue;
                mx = fmaxf(mx, (float)x2[((size_t)n * 196 + rr * 14 + cc) * 512 + c]);
            }
        }
        inT7[((size_t)n * 81 + sp) * 512 + c] = (__bf16)mx;
        xA[((size_t)n * 49 + p) * 512 + c] = mx;
    }
}

// ---------- fused attention + GN partial stats ----------
__global__ __launch_bounds__(256) void k_attvirt(
    const __bf16* __restrict__ qT, const __bf16* __restrict__ kT,
    const __bf16* __restrict__ vT, float* __restrict__ virt,
    float* __restrict__ statsRaw)
{
    const int p = blockIdx.y;
    const int w = threadIdx.x >> 6, m = threadIdx.x & 63;
    const int n = blockIdx.x * 4 + w;
    __shared__ float s_q[4][HIDC];
    __shared__ float s_a[4][64];
    {
        const uint4 v = ((const uint4*)(qT + ((size_t)p * 64 + n) * HIDC))[m];
        const unsigned* u = (const unsigned*)&v;
#pragma unroll
        for (int j = 0; j < 4; ++j) {
            s_q[w][m * 8 + 2 * j]     = bf2f((unsigned short)(u[j] & 0xffff));
            s_q[w][m * 8 + 2 * j + 1] = bf2f((unsigned short)(u[j] >> 16));
        }
    }
    __syncthreads();
    const uint4* krow = (const uint4*)(kT + ((size_t)p * 64 + m) * HIDC);
    float acc0 = 0.f, acc1 = 0.f;
    for (int i = 0; i < 64; ++i) {
        const uint4 v = krow[i];
        const unsigned* u = (const unsigned*)&v;
#pragma unroll
        for (int j = 0; j < 2; ++j) {
            acc0 = fmaf(s_q[w][i * 8 + 2 * j],     bf2f((unsigned short)(u[j] & 0xffff)), acc0);
            acc0 = fmaf(s_q[w][i * 8 + 2 * j + 1], bf2f((unsigned short)(u[j] >> 16)),    acc0);
        }
#pragma unroll
        for (int j = 2; j < 4; ++j) {
            acc1 = fmaf(s_q[w][i * 8 + 2 * j],     bf2f((unsigned short)(u[j] & 0xffff)), acc1);
            acc1 = fmaf(s_q[w][i * 8 + 2 * j + 1], bf2f((unsigned short)(u[j] >> 16)),    acc1);
        }
    }
    float acc = (acc0 + acc1) * 0.044194173824159216f;
    float mx = acc;
#pragma unroll
    for (int off = 32; off; off >>= 1) mx = fmaxf(mx, __shfl_xor(mx, off));
    const float e = expf(acc - mx);
    float s = e;
#pragma unroll
    for (int off = 32; off; off >>= 1) s += __shfl_xor(s, off);
    s_a[w][m] = e / s;
    __syncthreads();
    const int c0 = m * 8;
    float av[8];
#pragma unroll
    for (int j = 0; j < 8; ++j) av[j] = 0.f;
    for (int mm = 0; mm < 64; ++mm) {
        const float a = s_a[w][mm];
        const uint4 v = *(const uint4*)(vT + ((size_t)p * 64 + mm) * HIDC + c0);
        const unsigned* u = (const unsigned*)&v;
#pragma unroll
        for (int j = 0; j < 4; ++j) {
            av[2 * j]     = fmaf(a, bf2f((unsigned short)(u[j] & 0xffff)), av[2 * j]);
            av[2 * j + 1] = fmaf(a, bf2f((unsigned short)(u[j] >> 16)),    av[2 * j + 1]);
        }
    }
    float* o = virt + ((size_t)n * 49 + p) * 512 + c0;
    float ps = 0.f, pq = 0.f;
#pragma unroll
    for (int j = 0; j < 8; ++j) {
        o[j] = av[j];
        ps += av[j];
        pq = fmaf(av[j], av[j], pq);
    }
#pragma unroll
    for (int off = 32; off; off >>= 1) {
        ps += __shfl_xor(ps, off);
        pq += __shfl_xor(pq, off);
    }
    if (m == 0) {
        atomicAdd(statsRaw + n * 2, ps);
        atomicAdd(statsRaw + n * 2 + 1, pq);
    }
}

// ---------- final fc: out[n][k] = [relu(roi) | gap/49] . wfc2[k] ----------
__global__ __launch_bounds__(256) void k_final(
    const float* __restrict__ roi, const float* __restrict__ gap,
    const float* __restrict__ wfc2, float* __restrict__ out)
{
    const int n = blockIdx.x, tid = threadIdx.x;
    __shared__ float s[1024];
    // R30: roi is now the un-relu'd split-K accumulation -> relu here.
    s[tid]       = fmaxf(roi[(size_t)n * 512 + tid], 0.f);
    s[tid + 256] = fmaxf(roi[(size_t)n * 512 + 256 + tid], 0.f);
    s[tid + 512] = gap[(size_t)n * 512 + tid] * (1.f / 49.f);
    s[tid + 768] = gap[(size_t)n * 512 + 256 + tid] * (1.f / 49.f);
    __syncthreads();
    if (tid < 240) {
        const int k = tid >> 2, part = tid & 3;
        const float4* w4 = (const float4*)(wfc2 + (size_t)k * 1024 + part * 256);
        const float4* s4 = (const float4*)(s + part * 256);
        float a0 = 0.f, a1 = 0.f, a2 = 0.f, a3 = 0.f;
        for (int i = 0; i < 64; ++i) {
            const float4 wv = w4[i], sv = s4[i];
            a0 = fmaf(wv.x, sv.x, a0); a1 = fmaf(wv.y, sv.y, a1);
            a2 = fmaf(wv.z, sv.z, a2); a3 = fmaf(wv.w, sv.w, a3);
        }
        float acc = (a0 + a1) + (a2 + a3);
        acc += __shfl_xor(acc, 1);
        acc += __shfl_xor(acc, 2);
        if (part == 0) out[n * NCLS + k] = acc;
    }
}

// ---------------------------------------------------------------------------
extern "C" void kernel_launch(void* const* d_in, const int* in_sizes, int n_in,
                              void* d_out, int out_size, void* d_ws, size_t ws_size,
                              hipStream_t stream) {
    const float* bg    = (const float*)d_in[0];
    const float* actor = (const float*)d_in[1];
    const float* w1    = (const float*)d_in[2];
    const float* w2    = (const float*)d_in[3];
    const float* wq    = (const float*)d_in[4];
    const float* wk    = (const float*)d_in[5];
    const float* wv    = (const float*)d_in[6];
    const float* wo    = (const float*)d_in[7];
    const float* gamma = (const float*)d_in[8];
    const float* beta  = (const float*)d_in[9];
    const float* wfc1  = (const float*)d_in[10];
    const float* wfc2  = (const float*)d_in[11];
    float* out = (float*)d_out;
    float* ws  = (float*)d_ws;

    // ---- fp32 regions (R30: A_T/Bp/roi adjacent -> one memset) ----
    float* A_T   = ws;                        // 131,072
    float* Bp    = A_T + 131072;              // 32,768
    float* roi   = Bp + 32768;                // 32,768 (un-relu'd split-K acc)
    float* xA    = roi + 32768;               // PLANE
    float* xB    = xA + PLANE;                // PLANE
    float* stats = xB + PLANE;                // 128
    float* gap   = stats + 128;               // 32,768
    float* fend  = gap + 32768;
    // ---- bf16 regions ----
    __bf16* x2h  = (__bf16*)fend;             // 64*196*512 = 6,422,528 halves
    float*  virt = (float*)x2h;               // aliases x2h (dead after pool)
    __bf16* inT2 = x2h + 6422528;             // 256*81*512 = 10,616,832
    __bf16* qkvT = inT2;                      // aliases inT2 (dead after conv2)
    __bf16* inT7 = inT2 + 10616832;           // 64*81*512  = 2,654,208
    __bf16* wAll = inT7 + 2654208;            // 9*4608*512 = 21,233,664
    __bf16* gnT  = wAll + (size_t)9 * OCALL * 512 + 262144;

    // 0: zero split-K accumulators (A_T+Bp+roi contiguous, 786KB)
    hipMemsetAsync(ws, 0, (size_t)196608 * sizeof(float), stream);
    // 1: split-K ab GEMM + weight transpose + inT7 borders (merged)
    k_mega<<<5312, 256, 0, stream>>>(bg, actor, w1, wfc1, w2, wq, wk, wv, wo,
                                     A_T, Bp, roi, wAll, inT7);
    // 2: conv2 input planes
    k_prep_in2<<<dim3(256, 3), 256, 0, stream>>>(A_T, Bp, inT2);
    // 3: conv2 — 3-phase pipelined, VN4/OCT4 (64,8)=512 wgs = 2/CU
    k_conv_pipe<4, 2, 4><<<dim3(64, 8), 256, 0, stream>>>(
        inT2, wAll, 0, x2h, nullptr, nullptr,
        nullptr, nullptr, nullptr, nullptr);
    // 4: pool + pack + residual
    k_pool_prep<<<64 * 49, 256, 0, stream>>>(x2h, inT7, xA);

    float* xin = xA;
    float* xout = xB;
    for (int d = 0; d < 2; ++d) {
        // 5/8: fused qkv — 3-phase pipelined, VN2/OCT4 (32,24)=768 wgs = 3/CU
        k_conv_pipe<2, 0, 4><<<dim3(32, 24), 256, 0, stream>>>(
            inT7, wAll, 512 + d * 2048, qkvT, stats,
            d == 1 ? gap : nullptr,
            nullptr, nullptr, nullptr, nullptr);
        // 6/9: attention + GN partial stats
        k_attvirt<<<dim3(16, 49), 256, 0, stream>>>(
            qkvT, qkvT + PLANE, qkvT + 2 * PLANE, virt, stats);
        // 6.5/9.5: GN+relu materialization for wo pipe
        k_prep_gn<<<dim3(64, 9), 256, 0, stream>>>(
            virt, stats, gamma + d * HIDC, beta + d * HIDC, gnT);
        // 7/10: wo conv — VN2/OCT2 oc-split: (32,16)=512 wgs = 2/CU
        k_conv_pipe<2, 1, 2><<<dim3(32, 16), 256, 0, stream>>>(
            gnT, wAll, 2048 + d * 2048, nullptr, nullptr, nullptr,
            xin, xout, d == 0 ? inT7 : nullptr, d == 1 ? gap : nullptr);
        float* t = xin; xin = xout; xout = t;
    }
    // 11: final fc from relu(roi) + fused gap
    k_final<<<64, 256, 0, stream>>>(roi, gap, wfc2, out);
}